// Round 1
// baseline (218.879 us; speedup 1.0000x reference)
//
#include <hip/hip_runtime.h>

// Problem constants
#define G   128
#define A   100
#define WIN 10
#define FD  16
#define H   128
#define NROWS (G*A)          // 12800
#define K1  (WIN*FD)         // 160

// ---------------------------------------------------------------------------
// Kernel 1: per-group normalized adjacency
//   r[a][w] = x[(g*A+a)*WIN*FD + w*FD + 15]
//   corr via centered rows; adj = 1 - |corr| + I; nadj = D^-1/2 adj D^-1/2
// ---------------------------------------------------------------------------
__global__ __launch_bounds__(256) void k_nadj(const float* __restrict__ x,
                                              float* __restrict__ nadj) {
    __shared__ float xc[A][WIN];      // centered returns
    __shared__ float invn[A];
    __shared__ float adjs[A][A + 1];  // +1 pad
    __shared__ float dinv[A];
    const int g = blockIdx.x;
    const int t = threadIdx.x;

    for (int idx = t; idx < A * WIN; idx += 256) {
        int a = idx / WIN, w = idx % WIN;
        xc[a][w] = x[((g * A + a) * WIN + w) * FD + (FD - 1)];
    }
    __syncthreads();
    if (t < A) {
        float m = 0.f;
        #pragma unroll
        for (int w = 0; w < WIN; w++) m += xc[t][w];
        m *= (1.0f / WIN);
        float ss = 0.f;
        #pragma unroll
        for (int w = 0; w < WIN; w++) {
            float v = xc[t][w] - m;
            xc[t][w] = v;
            ss += v * v;
        }
        invn[t] = rsqrtf(ss);
    }
    __syncthreads();
    for (int idx = t; idx < A * A; idx += 256) {
        int i = idx / A, j = idx % A;
        float dot = 0.f;
        #pragma unroll
        for (int w = 0; w < WIN; w++) dot += xc[i][w] * xc[j][w];
        float corr = dot * invn[i] * invn[j];
        float v = 1.0f - fabsf(corr);
        if (i == j) v += 1.0f;
        adjs[i][j] = v;
    }
    __syncthreads();
    if (t < A) {
        float s = 0.f;
        for (int j = 0; j < A; j++) s += adjs[t][j];
        dinv[t] = rsqrtf(s);
    }
    __syncthreads();
    for (int idx = t; idx < A * A; idx += 256) {
        int i = idx / A, j = idx % A;
        nadj[g * A * A + idx] = dinv[i] * adjs[i][j] * dinv[j];
    }
}

// ---------------------------------------------------------------------------
// Kernel 2: Y = X @ W   (X: [NROWS, K], W: [K, 128], Y: [NROWS, 128])
// BM=16 rows per block, K chunked by 32, 2x4 register tile per thread.
// ---------------------------------------------------------------------------
#define BM 16
#define BK 32
__global__ __launch_bounds__(256) void k_gemm(const float* __restrict__ X,
                                              const float* __restrict__ W,
                                              float* __restrict__ Y, int K) {
    __shared__ float Xs[BM][BK + 4];   // stride 36 -> f4-aligned, conflict-safe
    __shared__ float Ws[BK][H];
    const int t = threadIdx.x;
    const int n0 = blockIdx.x * BM;
    const int cg = t % 32, rg = t / 32;  // cg: 0..31, rg: 0..7
    const int c0 = cg * 4;
    const int r0 = rg * 2;

    float acc[2][4] = {};

    for (int k0 = 0; k0 < K; k0 += BK) {
        if (t < 128) {
            int r = t / 8, c4 = (t % 8) * 4;
            *(float4*)(&Xs[r][c4]) = *(const float4*)(X + (n0 + r) * K + k0 + c4);
        }
        #pragma unroll
        for (int i = 0; i < 4; i++) {
            int e = t + i * 256;               // 1024 f4 = 32x128 floats
            int kk = e / 32, c4 = (e % 32) * 4;
            *(float4*)(&Ws[kk][c4]) = *(const float4*)(W + (k0 + kk) * H + c4);
        }
        __syncthreads();
        #pragma unroll
        for (int kk = 0; kk < BK; kk++) {
            float4 wv = *(const float4*)(&Ws[kk][c0]);
            float x0 = Xs[r0][kk];
            float x1 = Xs[r0 + 1][kk];
            acc[0][0] += x0 * wv.x; acc[0][1] += x0 * wv.y;
            acc[0][2] += x0 * wv.z; acc[0][3] += x0 * wv.w;
            acc[1][0] += x1 * wv.x; acc[1][1] += x1 * wv.y;
            acc[1][2] += x1 * wv.z; acc[1][3] += x1 * wv.w;
        }
        __syncthreads();
    }
    #pragma unroll
    for (int r = 0; r < 2; r++) {
        float4 o = make_float4(acc[r][0], acc[r][1], acc[r][2], acc[r][3]);
        *(float4*)(Y + (n0 + r0 + r) * H + c0) = o;
    }
}

// ---------------------------------------------------------------------------
// Kernel 3: Z[g,i,:] = relu(b + sum_j nadj[g,i,j] * Y[g,j,:])
// grid (G, 2): 50 rows per block; 320 threads; 5x4 register tile.
// ---------------------------------------------------------------------------
__global__ __launch_bounds__(320) void k_agg(const float* __restrict__ nadj,
                                             const float* __restrict__ Y,
                                             const float* __restrict__ bias,
                                             float* __restrict__ Z) {
    __shared__ float Ys[A][H];        // 51.2 KB
    __shared__ float ns[50][A];       // 20 KB
    const int g = blockIdx.x;
    const int i0 = blockIdx.y * 50;
    const int t = threadIdx.x;

    const float* Yg = Y + g * A * H;
    for (int i = t; i < A * H / 4; i += 320)
        ((float4*)Ys)[i] = ((const float4*)Yg)[i];
    const float* ng = nadj + g * A * A + i0 * A;
    for (int i = t; i < 50 * A / 4; i += 320)
        ((float4*)ns)[i] = ((const float4*)ng)[i];
    __syncthreads();

    const int cg = t % 32, rg = t / 32;   // rg: 0..9
    const int c0 = cg * 4;
    const int r0 = rg * 5;

    float acc[5][4] = {};
    for (int j = 0; j < A; j++) {
        float4 yv = *(const float4*)(&Ys[j][c0]);
        float nv[5];
        #pragma unroll
        for (int r = 0; r < 5; r++) nv[r] = ns[r0 + r][j];
        #pragma unroll
        for (int r = 0; r < 5; r++) {
            acc[r][0] += nv[r] * yv.x; acc[r][1] += nv[r] * yv.y;
            acc[r][2] += nv[r] * yv.z; acc[r][3] += nv[r] * yv.w;
        }
    }
    float4 bv = *(const float4*)(bias + c0);
    #pragma unroll
    for (int r = 0; r < 5; r++) {
        float4 o;
        o.x = fmaxf(0.f, acc[r][0] + bv.x);
        o.y = fmaxf(0.f, acc[r][1] + bv.y);
        o.z = fmaxf(0.f, acc[r][2] + bv.z);
        o.w = fmaxf(0.f, acc[r][3] + bv.w);
        *(float4*)(Z + (g * A + i0 + r0 + r) * H + c0) = o;
    }
}

// ---------------------------------------------------------------------------
// Kernel 4: fused conv1(1x3, pad 1 along H) + relu + conv2(1x3, pad 1)
// One wave per row n; lane handles columns j0=2*lane, j1=j0+1.
// conv1 taps shared between neighbor lanes via shuffles.
// ---------------------------------------------------------------------------
__global__ __launch_bounds__(256) void k_conv(const float* __restrict__ h3,
                                              const float* __restrict__ cw1,
                                              const float* __restrict__ cb1,
                                              const float* __restrict__ cw2,
                                              const float* __restrict__ cb2,
                                              float* __restrict__ out) {
    const int wave = threadIdx.x >> 6;
    const int lane = threadIdx.x & 63;
    const int n = blockIdx.x * 4 + wave;
    const float* hr = h3 + n * H;
    const int j0 = lane * 2;

    // h[j0-1 .. j0+2], zero-padded at the edges (conv1's own padding)
    float a1 = (j0 >= 1) ? hr[j0 - 1] : 0.f;
    float a2 = hr[j0];
    float a3 = hr[j0 + 1];
    float a4 = (j0 + 2 < H) ? hr[j0 + 2] : 0.f;

    float acc0 = cb2[0], acc1 = cb2[0];

    for (int c = 0; c < H; c++) {
        float b  = cb1[c];
        float w0 = cw1[3 * c], w1 = cw1[3 * c + 1], w2 = cw1[3 * c + 2];
        // t at j0 and j1
        float t0 = fmaxf(0.f, fmaf(w2, a3, fmaf(w1, a2, fmaf(w0, a1, b))));
        float t1 = fmaxf(0.f, fmaf(w2, a4, fmaf(w1, a3, fmaf(w0, a2, b))));
        // neighbors: t[j0-1] from lane-1's t1, t[j1+1] from lane+1's t0
        float tm = __shfl_up(t1, 1);
        float tp = __shfl_down(t0, 1);
        if (lane == 0)  tm = 0.f;   // conv2 zero-pad at j=-1
        if (lane == 63) tp = 0.f;   // conv2 zero-pad at j=128
        float v0 = cw2[3 * c], v1 = cw2[3 * c + 1], v2 = cw2[3 * c + 2];
        acc0 = fmaf(v0, tm, acc0); acc0 = fmaf(v1, t0, acc0); acc0 = fmaf(v2, t1, acc0);
        acc1 = fmaf(v0, t0, acc1); acc1 = fmaf(v1, t1, acc1); acc1 = fmaf(v2, tp, acc1);
    }
    float2 o = make_float2(acc0, acc1);
    *(float2*)(out + n * H + j0) = o;
}

// ---------------------------------------------------------------------------
extern "C" void kernel_launch(void* const* d_in, const int* in_sizes, int n_in,
                              void* d_out, int out_size, void* d_ws, size_t ws_size,
                              hipStream_t stream) {
    const float* x   = (const float*)d_in[0];
    const float* W1  = (const float*)d_in[1];
    const float* b1  = (const float*)d_in[2];
    const float* W2  = (const float*)d_in[3];
    const float* b2  = (const float*)d_in[4];
    const float* W3  = (const float*)d_in[5];
    const float* b3  = (const float*)d_in[6];
    const float* cw1 = (const float*)d_in[7];
    const float* cb1 = (const float*)d_in[8];
    const float* cw2 = (const float*)d_in[9];
    const float* cb2 = (const float*)d_in[10];
    float* out = (float*)d_out;

    float* ws   = (float*)d_ws;
    float* nadj = ws;                         // G*A*A      = 1,280,000 floats
    float* bufY = nadj + (size_t)G * A * A;   // NROWS*H    = 1,638,400 floats
    float* bufZ = bufY + (size_t)NROWS * H;   // NROWS*H

    k_nadj<<<G, 256, 0, stream>>>(x, nadj);

    // Layer 1: Y = x(feats) @ W1 ; Z = relu(nadj @ Y + b1)
    k_gemm<<<NROWS / BM, 256, 0, stream>>>(x, W1, bufY, K1);
    k_agg<<<dim3(G, 2), 320, 0, stream>>>(nadj, bufY, b1, bufZ);

    // Layer 2
    k_gemm<<<NROWS / BM, 256, 0, stream>>>(bufZ, W2, bufY, H);
    k_agg<<<dim3(G, 2), 320, 0, stream>>>(nadj, bufY, b2, bufZ);

    // Layer 3
    k_gemm<<<NROWS / BM, 256, 0, stream>>>(bufZ, W3, bufY, H);
    k_agg<<<dim3(G, 2), 320, 0, stream>>>(nadj, bufY, b3, bufZ);

    // Fused conv1 + relu + conv2
    k_conv<<<NROWS / 4, 256, 0, stream>>>(bufZ, cw1, cb1, cw2, cb2, out);
}